// Round 10
// baseline (91.836 us; speedup 1.0000x reference)
//
#include <hip/hip_runtime.h>
#include <hip/hip_bf16.h>

#define N_NODES 262144
#define N_GRAPHS 256
#define DMODEL 256
#define LOG2_F 0.69314718055994530942f

typedef __attribute__((ext_vector_type(4))) float f32x4;
typedef __attribute__((ext_vector_type(8))) short short8;

__device__ __forceinline__ short bf(float x) {
    __hip_bfloat16 h = __float2bfloat16(x);
    return __builtin_bit_cast(short, h);
}

__device__ __forceinline__ short8 cvt8(f32x4 lo, f32x4 hi) {
    short8 a;
    a[0] = bf(lo[0]); a[1] = bf(lo[1]); a[2] = bf(lo[2]); a[3] = bf(lo[3]);
    a[4] = bf(hi[0]); a[5] = bf(hi[1]); a[6] = bf(hi[2]); a[7] = bf(hi[3]);
    return a;
}

// One bfrag read feeds TWO MFMAs (m0/m1 row-fragments) -> halves LDS traffic.
__device__ __forceinline__ void mfma16(short8 a0, short8 a1, const char* bb,
                                       f32x4* accA, f32x4* accB) {
#pragma unroll
    for (int nt = 0; nt < 8; ++nt) {
        short8 bfrag = *reinterpret_cast<const short8*>(bb + nt * 1024);
        accA[nt] = __builtin_amdgcn_mfma_f32_16x16x32_bf16(a0, bfrag, accA[nt], 0, 0, 0);
        accB[nt] = __builtin_amdgcn_mfma_f32_16x16x32_bf16(a1, bfrag, accB[nt], 0, 0, 0);
    }
}

// Pack g_enc (fp32 [G=256][D=256]) into bf16 B-fragments in MFMA lane order.
// chunk c = ks*16 + ntile (128 chunks of 1KB). Within chunk: lane*16B.
__global__ void pack_b_kernel(const float* __restrict__ g_enc,
                              short* __restrict__ bout) {
    int b = blockIdx.x;        // 0..127
    int lane = threadIdx.x;    // 0..63
    int ks = b >> 4, nt = b & 15;
    int g = nt * 16 + (lane & 15);
    int k = ks * 32 + (lane >> 4) * 8;
    const float* src = g_enc + g * DMODEL + k;
    short8 v;
#pragma unroll
    for (int j = 0; j < 8; ++j) v[j] = bf(src[j]);
    reinterpret_cast<short8*>(bout)[b * 64 + lane] = v;
}

// Per wave-pass: 32 rows x 128 cols. acc[2][8] = 64 accumulators (AGPR side).
// 8 waves = 4 row-stripes x 2 col-halves. Pass = 128 rows; 8 passes.
// A-pipeline: group-of-2 ks, named slots (2 ks x 2 m-frags x lo/hi = 32
// VGPRs); consuming group g issues group g+1's 8 loads (g=3 -> next pass's
// ks0/1, (pass+1)&7 wraps in-bounds). `#pragma unroll 1` on pass & group
// loops keeps scheduling regions small -> register-frugal (R8 lesson).
__global__ __launch_bounds__(512, 1) void mvgrl_main(
    const float* __restrict__ l_enc, const int* __restrict__ batch,
    const short* __restrict__ bpack, double* __restrict__ partials) {
    extern __shared__ char lds_raw[];  // 128KB: full B in fragment order

    const int tid = threadIdx.x;
    const int lane = tid & 63;
    const int wave = tid >> 6;   // 0..7
    const int wrow = wave & 3;   // row stripe (32 rows each)
    const int chalf = wave >> 2; // column half (128 cols each)

    // ---- stage entire B (128KB) into LDS once ----
    {
        const short8* bp = reinterpret_cast<const short8*>(bpack);
        short8* lb = reinterpret_cast<short8*>(lds_raw);
#pragma unroll
        for (int c = 0; c < 16; ++c) {
            int chunk = wave + c * 8;
            lb[chunk * 64 + lane] = bp[chunk * 64 + lane];
        }
    }
    __syncthreads();
    // no further barriers until final reduction

    const int row_blk = blockIdx.x * 1024;
    const char* ldsB = lds_raw + chalf * 8192 + lane * 16;
    double dSall = 0.0, dSpq = 0.0, dSpr = 0.0;

    // Named A-pipeline slots: e=even ks, o=odd ks; 0=m0 row-frag, 1=m1.
    f32x4 se0l, se0h, se1l, se1h, so0l, so0h, so1l, so1h;

    const int kofs = (lane >> 4) * 8;
    const float* arow = l_enc +
        (size_t)(row_blk + wrow * 32 + (lane & 15)) * DMODEL + kofs;
    const float* am1 = arow + 16 * DMODEL;
    se0l = *reinterpret_cast<const f32x4*>(arow + 0);
    se0h = *reinterpret_cast<const f32x4*>(arow + 4);
    se1l = *reinterpret_cast<const f32x4*>(am1 + 0);
    se1h = *reinterpret_cast<const f32x4*>(am1 + 4);
    so0l = *reinterpret_cast<const f32x4*>(arow + 32);
    so0h = *reinterpret_cast<const f32x4*>(arow + 36);
    so1l = *reinterpret_cast<const f32x4*>(am1 + 32);
    so1h = *reinterpret_cast<const f32x4*>(am1 + 36);

#pragma unroll 1
    for (int pass = 0; pass < 8; ++pass) {
        const int rowbase = row_blk + pass * 128 + wrow * 32;
        const int rsub = (lane >> 4) * 4;
        int bvA0 = batch[rowbase + rsub + 0];
        int bvA1 = batch[rowbase + rsub + 1];
        int bvA2 = batch[rowbase + rsub + 2];
        int bvA3 = batch[rowbase + rsub + 3];
        int bvB0 = batch[rowbase + 16 + rsub + 0];
        int bvB1 = batch[rowbase + 16 + rsub + 1];
        int bvB2 = batch[rowbase + 16 + rsub + 2];
        int bvB3 = batch[rowbase + 16 + rsub + 3];

        const float* arow_next = l_enc +
            (size_t)(row_blk + ((pass + 1) & 7) * 128 + wrow * 32 + (lane & 15)) *
                DMODEL + kofs;

        f32x4 accA[8], accB[8];
#pragma unroll
        for (int n = 0; n < 8; ++n) {
            accA[n] = (f32x4){0.f, 0.f, 0.f, 0.f};
            accB[n] = (f32x4){0.f, 0.f, 0.f, 0.f};
        }

#pragma unroll 1
        for (int g = 0; g < 4; ++g) {
            // refill source: group g+1's even ks (g=3 -> next pass ks0)
            const float* srcE = (g < 3) ? (arow + (2 * g + 2) * 32) : arow_next;
            const float* srcEm1 = srcE + 16 * DMODEL;
            // even ks = 2g
            {
                short8 a0 = cvt8(se0l, se0h);
                short8 a1 = cvt8(se1l, se1h);
                se0l = *reinterpret_cast<const f32x4*>(srcE + 0);
                se0h = *reinterpret_cast<const f32x4*>(srcE + 4);
                se1l = *reinterpret_cast<const f32x4*>(srcEm1 + 0);
                se1h = *reinterpret_cast<const f32x4*>(srcEm1 + 4);
                mfma16(a0, a1, ldsB + (size_t)(2 * g) * 16384, accA, accB);
            }
            // odd ks = 2g+1
            {
                short8 a0 = cvt8(so0l, so0h);
                short8 a1 = cvt8(so1l, so1h);
                so0l = *reinterpret_cast<const f32x4*>(srcE + 32);
                so0h = *reinterpret_cast<const f32x4*>(srcE + 36);
                so1l = *reinterpret_cast<const f32x4*>(srcEm1 + 32);
                so1h = *reinterpret_cast<const f32x4*>(srcEm1 + 36);
                mfma16(a0, a1, ldsB + (size_t)(2 * g + 1) * 16384, accA, accB);
            }
        }
        arow = arow_next;

        // ---- epilogue: q = softplus(r) - log2 ----
        // C/D: col = chalf*128 + nt*16 + (lane&15),
        //      rowA = rowbase + rsub + rg ; rowB = rowA + 16
        float Sall = 0.f, Spq = 0.f, Spr = 0.f;
        const int colbase = chalf * 128 + (lane & 15);
#pragma unroll
        for (int nt = 0; nt < 8; ++nt) {
            const int col = colbase + nt * 16;
            f32x4 avA = accA[nt];
            f32x4 avB = accB[nt];
            {
                float r = avA[0];
                float q = fmaxf(r, 0.f) - LOG2_F + __logf(1.f + __expf(-fabsf(r)));
                Sall += q; if (col == bvA0) { Spq += q; Spr += r; }
            }
            {
                float r = avA[1];
                float q = fmaxf(r, 0.f) - LOG2_F + __logf(1.f + __expf(-fabsf(r)));
                Sall += q; if (col == bvA1) { Spq += q; Spr += r; }
            }
            {
                float r = avA[2];
                float q = fmaxf(r, 0.f) - LOG2_F + __logf(1.f + __expf(-fabsf(r)));
                Sall += q; if (col == bvA2) { Spq += q; Spr += r; }
            }
            {
                float r = avA[3];
                float q = fmaxf(r, 0.f) - LOG2_F + __logf(1.f + __expf(-fabsf(r)));
                Sall += q; if (col == bvA3) { Spq += q; Spr += r; }
            }
            {
                float r = avB[0];
                float q = fmaxf(r, 0.f) - LOG2_F + __logf(1.f + __expf(-fabsf(r)));
                Sall += q; if (col == bvB0) { Spq += q; Spr += r; }
            }
            {
                float r = avB[1];
                float q = fmaxf(r, 0.f) - LOG2_F + __logf(1.f + __expf(-fabsf(r)));
                Sall += q; if (col == bvB1) { Spq += q; Spr += r; }
            }
            {
                float r = avB[2];
                float q = fmaxf(r, 0.f) - LOG2_F + __logf(1.f + __expf(-fabsf(r)));
                Sall += q; if (col == bvB2) { Spq += q; Spr += r; }
            }
            {
                float r = avB[3];
                float q = fmaxf(r, 0.f) - LOG2_F + __logf(1.f + __expf(-fabsf(r)));
                Sall += q; if (col == bvB3) { Spq += q; Spr += r; }
            }
        }
        dSall += (double)Sall;
        dSpq += (double)Spq;
        dSpr += (double)Spr;
    }

    // ---- reduction: wave shuffle -> LDS -> block partial ----
#pragma unroll
    for (int off = 32; off; off >>= 1) {
        dSall += __shfl_xor(dSall, off);
        dSpq += __shfl_xor(dSpq, off);
        dSpr += __shfl_xor(dSpr, off);
    }
    __syncthreads();  // everyone done reading B before LDS reuse
    double* red = reinterpret_cast<double*>(lds_raw);
    if (lane == 0) {
        red[wave * 3 + 0] = dSall;
        red[wave * 3 + 1] = dSpq;
        red[wave * 3 + 2] = dSpr;
    }
    __syncthreads();
    if (tid == 0) {
        double a = 0, b = 0, c = 0;
#pragma unroll
        for (int w = 0; w < 8; ++w) {
            a += red[w * 3 + 0];
            b += red[w * 3 + 1];
            c += red[w * 3 + 2];
        }
        partials[blockIdx.x * 3 + 0] = a;
        partials[blockIdx.x * 3 + 1] = b;
        partials[blockIdx.x * 3 + 2] = c;
    }
}

__global__ void finalize_kernel(const double* __restrict__ p,
                                float* __restrict__ out) {
    int t = threadIdx.x;  // 256 threads, one partial-triple each
    double a = p[t * 3 + 0], b = p[t * 3 + 1], c = p[t * 3 + 2];
#pragma unroll
    for (int off = 32; off; off >>= 1) {
        a += __shfl_xor(a, off);
        b += __shfl_xor(b, off);
        c += __shfl_xor(c, off);
    }
    __shared__ double red[12];
    int lane = t & 63, w = t >> 6;
    if (lane == 0) { red[w * 3] = a; red[w * 3 + 1] = b; red[w * 3 + 2] = c; }
    __syncthreads();
    if (t == 0) {
        double A = 0, B = 0, C = 0;
#pragma unroll
        for (int i = 0; i < 4; ++i) {
            A += red[i * 3]; B += red[i * 3 + 1]; C += red[i * 3 + 2];
        }
        // neg_sum = S_all - S_posq ; pos_sum = S_posr - S_posq
        double neg = (A - B) / ((double)N_NODES * (double)(N_GRAPHS - 1));
        double pos = (C - B) / (double)N_NODES;
        out[0] = (float)(neg - pos);
    }
}

extern "C" void kernel_launch(void* const* d_in, const int* in_sizes, int n_in,
                              void* d_out, int out_size, void* d_ws,
                              size_t ws_size, hipStream_t stream) {
    const float* l_enc = (const float*)d_in[0];
    const float* g_enc = (const float*)d_in[1];
    const int* batch = (const int*)d_in[2];
    float* out = (float*)d_out;

    short* bpack = (short*)d_ws;                           // 128KB
    double* partials = (double*)((char*)d_ws + 131072);    // 256*3 doubles

    hipFuncSetAttribute(reinterpret_cast<const void*>(mvgrl_main),
                        hipFuncAttributeMaxDynamicSharedMemorySize, 131072);

    pack_b_kernel<<<128, 64, 0, stream>>>(g_enc, bpack);
    mvgrl_main<<<256, 512, 131072, stream>>>(l_enc, batch, bpack, partials);
    finalize_kernel<<<1, 256, 0, stream>>>(partials, out);
}